// Round 3
// baseline (319.198 us; speedup 1.0000x reference)
//
#include <hip/hip_runtime.h>
#include <hip/hip_bf16.h>
#include <math.h>

#define BB 2
#define LL 2048
#define DD 256
#define NT (BB*LL)      // 4096 tokens
#define HCOLS 896       // ke(256) qe(256) lke(256) gate(128)
#define NCOLS 1152      // HCOLS + v(256)
#define FDIM 80         // 32 bank + 8 joint + 32 pos + 8 pad
#define CC 64           // chunk length
#define NC (NT/CC)      // 64 chunks total (chunks never straddle batch: CC | LL)
#define NCB (LL/CC)     // 32 chunks per batch
#define SST (FDIM*DD)   // 20480 floats per chunk state
#define PI_F 3.14159265358979323846f

__device__ __forceinline__ float gelu_erf(float v) {
    return 0.5f * v * (1.0f + erff(v * 0.70710678118654752440f));
}
__device__ __forceinline__ float sigmoidf_(float v) {
    return 1.0f / (1.0f + expf(-v));
}

// ---------------- K1: first layers: H = gelu(X@W1+b1) for ke/qe/lke/gate, V = X@v_w+v_b
// 16 tokens/block, 5 column strips/thread: 80 FMA per 5 weight loads.
__global__ __launch_bounds__(256) void k1_first(
    const float* __restrict__ x,
    const float* __restrict__ ke_w1, const float* __restrict__ ke_b1,
    const float* __restrict__ qe_w1, const float* __restrict__ qe_b1,
    const float* __restrict__ lke_w1, const float* __restrict__ lke_b1,
    const float* __restrict__ gate_w1, const float* __restrict__ gate_b1,
    const float* __restrict__ v_w, const float* __restrict__ v_b,
    float* __restrict__ H, float* __restrict__ V)
{
    __shared__ float xs[DD][16];    // transposed: [k][t], rows 64B (float4-readable)
    const int tid = threadIdx.x;
    const int t0 = blockIdx.x * 16;
    {
        int t = tid >> 4, k0 = (tid & 15) * 16;
        const float4* xp = reinterpret_cast<const float4*>(x + (size_t)(t0 + t) * DD + k0);
        #pragma unroll
        for (int j = 0; j < 4; ++j) {
            float4 v = xp[j];
            xs[k0 + 4 * j + 0][t] = v.x;
            xs[k0 + 4 * j + 1][t] = v.y;
            xs[k0 + 4 * j + 2][t] = v.z;
            xs[k0 + 4 * j + 3][t] = v.w;
        }
    }
    __syncthreads();

    const float* wbase[5];
    int ldw[5];
    bool valid[5];
    #pragma unroll
    for (int i = 0; i < 5; ++i) {
        int c = tid + 256 * i;
        valid[i] = (c < NCOLS);
        const float* bp; int ld = 256;
        if (c < 256)       { bp = ke_w1 + c; }
        else if (c < 512)  { bp = qe_w1 + (c - 256); }
        else if (c < 768)  { bp = lke_w1 + (c - 512); }
        else if (c < 896)  { bp = gate_w1 + (c - 768); ld = 128; }
        else if (c < 1152) { bp = v_w + (c - 896); }
        else               { bp = v_w; }  // dummy valid memory, result unused
        wbase[i] = bp; ldw[i] = ld;
    }

    float acc[5][16];
    #pragma unroll
    for (int i = 0; i < 5; ++i)
        #pragma unroll
        for (int t = 0; t < 16; ++t) acc[i][t] = 0.0f;

    #pragma unroll 2
    for (int k = 0; k < DD; ++k) {
        float w_[5];
        #pragma unroll
        for (int i = 0; i < 5; ++i) w_[i] = wbase[i][(size_t)k * ldw[i]];
        #pragma unroll
        for (int g = 0; g < 4; ++g) {
            float4 xv = *reinterpret_cast<const float4*>(&xs[k][4 * g]);
            #pragma unroll
            for (int i = 0; i < 5; ++i) {
                acc[i][4 * g + 0] += w_[i] * xv.x;
                acc[i][4 * g + 1] += w_[i] * xv.y;
                acc[i][4 * g + 2] += w_[i] * xv.z;
                acc[i][4 * g + 3] += w_[i] * xv.w;
            }
        }
    }

    #pragma unroll
    for (int i = 0; i < 5; ++i) {
        int c = tid + 256 * i;
        if (!valid[i]) continue;
        float bia;
        if (c < 256)      bia = ke_b1[c];
        else if (c < 512) bia = qe_b1[c - 256];
        else if (c < 768) bia = lke_b1[c - 512];
        else if (c < 896) bia = gate_b1[c - 768];
        else              bia = v_b[c - 896];
        #pragma unroll
        for (int t = 0; t < 16; ++t) {
            float v = acc[i][t] + bia;
            int tok = t0 + t;
            if (c < 896) H[(size_t)tok * HCOLS + c] = gelu_erf(v);
            else         V[(size_t)tok * DD + (c - 896)] = v;
        }
    }
}

// ---------------- K2: second layers -> phases -> feature vectors
__global__ __launch_bounds__(256) void k2_second(
    const float* __restrict__ H,
    const float* __restrict__ ke_w2, const float* __restrict__ ke_b2,
    const float* __restrict__ qe_w2, const float* __restrict__ qe_b2,
    const float* __restrict__ lke_w2, const float* __restrict__ lke_b2,
    const float* __restrict__ gate_w2, const float* __restrict__ gate_b2,
    const float* __restrict__ set_weights, const float* __restrict__ pos_weight,
    const float* __restrict__ ltm_weight, const float* __restrict__ ltm_count,
    const float* __restrict__ pos_freqs,
    float* __restrict__ Fk, float* __restrict__ Fq, float* __restrict__ Fql)
{
    __shared__ float hs[4][HCOLS];
    __shared__ float ph[4][49];   // 0..15 phi_k, 16..31 phi_q, 32..47 phi_ltm, 48 gate
    const int tid = threadIdx.x;
    const int w = tid >> 6;
    const int lane = tid & 63;
    const int t = blockIdx.x * 4 + w;

    for (int i = lane; i < HCOLS; i += 64) hs[w][i] = H[(size_t)t * HCOLS + i];
    __syncthreads();

    float val = 0.0f;
    if (lane < 16) {
        float a = ke_b2[lane];
        for (int k = 0; k < 256; ++k) a += hs[w][k] * ke_w2[k * 16 + lane];
        val = tanhf(a) * PI_F;
    } else if (lane < 32) {
        int o = lane - 16;
        float a = qe_b2[o];
        for (int k = 0; k < 256; ++k) a += hs[w][256 + k] * qe_w2[k * 16 + o];
        val = tanhf(a) * PI_F;
    } else if (lane < 48) {
        int o = lane - 32;
        float a = lke_b2[o];
        for (int k = 0; k < 256; ++k) a += hs[w][512 + k] * lke_w2[k * 16 + o];
        val = tanhf(a) * PI_F;
    } else if (lane == 48) {
        float a = gate_b2[0];
        for (int k = 0; k < 128; ++k) a += hs[w][768 + k] * gate_w2[k];
        val = sigmoidf_(a);
    }
    if (lane < 49) ph[w][lane] = val;
    __syncthreads();

    float sw[4];
    {
        float s0 = set_weights[0], s1 = set_weights[1], s2 = set_weights[2], s3 = set_weights[3];
        float mx = fmaxf(fmaxf(s0, s1), fmaxf(s2, s3));
        float e0 = expf(s0 - mx), e1 = expf(s1 - mx), e2 = expf(s2 - mx), e3 = expf(s3 - mx);
        float inv = 1.0f / (e0 + e1 + e2 + e3);
        sw[0] = e0 * inv; sw[1] = e1 * inv; sw[2] = e2 * inv; sw[3] = e3 * inv;
    }
    const float g = ph[w][48];
    const float aq = g * 0.2f;                                  // gate / (N_SETS+1)
    const float apos = (1.0f - g) * sigmoidf_(pos_weight[0]);
    const float altm = sigmoidf_(ltm_weight[0]) / sqrtf(fmaxf(ltm_count[0], 1.0f) * 16.0f);
    const int l = t & (LL - 1);
    float* fkr  = Fk  + (size_t)t * FDIM;
    float* fqr  = Fq  + (size_t)t * FDIM;
    float* fqlr = Fql + (size_t)t * 32;

    if (lane < 16) {
        int p = lane;
        float sk, ck; sincosf(ph[w][p], &sk, &ck);
        fkr[2 * p] = ck; fkr[2 * p + 1] = sk;
        float sq, cq; sincosf(ph[w][16 + p], &sq, &cq);
        float wq = aq * sw[p >> 2];
        fqr[2 * p] = wq * cq; fqr[2 * p + 1] = wq * sq;
        float sl, cl; sincosf(ph[w][32 + p], &sl, &cl);
        fqlr[2 * p] = altm * cl; fqlr[2 * p + 1] = altm * sl;
        float th = (float)l * pos_freqs[p] * (2.0f * PI_F);
        float sp, cp; sincosf(th, &sp, &cp);
        fkr[40 + 2 * p] = cp; fkr[41 + 2 * p] = sp;
        fqr[40 + 2 * p] = apos * cp; fqr[41 + 2 * p] = apos * sp;
    } else if (lane < 20) {
        int p = lane - 16;
        float pjk = ph[w][p] + ph[w][p + 4] + ph[w][p + 8] + ph[w][p + 12];
        float pjq = ph[w][16 + p] + ph[w][20 + p] + ph[w][24 + p] + ph[w][28 + p];
        float sjk, cjk; sincosf(pjk, &sjk, &cjk);
        float sjq, cjq; sincosf(pjq, &sjq, &cjq);
        fkr[32 + 2 * p] = cjk; fkr[33 + 2 * p] = sjk;
        fqr[32 + 2 * p] = aq * cjq; fqr[33 + 2 * p] = aq * sjq;
    } else if (lane < 24) {
        int p = lane - 20;
        fkr[72 + 2 * p] = 0.0f; fkr[73 + 2 * p] = 0.0f;
        fqr[72 + 2 * p] = 0.0f; fqr[73 + 2 * p] = 0.0f;
    }
}

// ---------------- K3: exclusive scan of joint-key phasors -> write gate -> scale Fk[0..39]
__global__ __launch_bounds__(512) void k3_scan(
    float* __restrict__ Fk,
    const float* __restrict__ resonance_scale, const float* __restrict__ resonance_threshold,
    const float* __restrict__ surprise_scale, const float* __restrict__ surprise_bias)
{
    __shared__ float km[8][LL];
    const int b = blockIdx.x;
    const int tid = threadIdx.x;
    const int w = tid >> 6;     // series: 32 + w in Fk dims (2p+comp)
    const int lane = tid & 63;
    {
        float v[32];
        float s = 0.0f;
        const float* src = Fk + (size_t)(b * LL) * FDIM + 32 + w;
        int l0 = lane * 32;
        #pragma unroll 4
        for (int i = 0; i < 32; ++i) { v[i] = src[(size_t)(l0 + i) * FDIM]; s += v[i]; }
        float local = s;
        #pragma unroll
        for (int off = 1; off < 64; off <<= 1) {
            float n = __shfl_up(s, off);
            if (lane >= off) s += n;
        }
        float run = s - local;   // exclusive base
        #pragma unroll 4
        for (int i = 0; i < 32; ++i) { km[w][l0 + i] = run; run += v[i]; }
    }
    __syncthreads();
    const float sc  = fminf(fmaxf(resonance_scale[0], 1.0f), 20.0f);
    const float th  = fminf(fmaxf(resonance_threshold[0], 0.1f), 0.9f);
    const float ssc = surprise_scale[0];
    const float sbi = surprise_bias[0];
    for (int q = 0; q < 4; ++q) {
        int l = tid + 512 * q;
        float rm = 0.0f;
        #pragma unroll
        for (int p = 0; p < 4; ++p) {
            float re = km[2 * p][l], im = km[2 * p + 1][l];
            rm += sqrtf(re * re + im * im);
        }
        rm *= 0.25f;
        float nr = rm / sqrtf(fmaxf((float)l, 1.0f));
        float sur = 0.5f * (1.0f - tanhf(sc * (nr - th)));
        float wg = sigmoidf_(ssc * (sur - 0.5f) + sbi);
        float4* row = reinterpret_cast<float4*>(Fk + (size_t)(b * LL + l) * FDIM);
        #pragma unroll
        for (int j = 0; j < 10; ++j) {   // dims 0..39 (bank+joint); pos dims untouched
            float4 vv = row[j];
            vv.x *= wg; vv.y *= wg; vv.z *= wg; vv.w *= wg;
            row[j] = vv;
        }
    }
}

// ---------------- K4a: per-chunk key state S_c = F_k_c^T @ V_c   (80 x 256)
__global__ __launch_bounds__(256) void k4a_state(
    const float* __restrict__ Fk, const float* __restrict__ V, float* __restrict__ S)
{
    __shared__ __align__(16) float fk[CC][FDIM];
    const int c = blockIdx.x;
    const int f0 = blockIdx.y * 20;       // f quarter: 20 floats = 80B, 16B-aligned
    const int tid = threadIdx.x;          // = output dim d
    for (int i = tid; i < CC * FDIM; i += 256) {
        int r = i / FDIM, cx = i - r * FDIM;
        fk[r][cx] = Fk[(size_t)c * CC * FDIM + i];
    }
    __syncthreads();
    float acc[20];
    #pragma unroll
    for (int f = 0; f < 20; ++f) acc[f] = 0.0f;
    const float* vp = V + (size_t)c * CC * DD + tid;
    for (int r = 0; r < CC; ++r) {
        float v = vp[(size_t)r * DD];
        #pragma unroll
        for (int g = 0; g < 5; ++g) {
            float4 q = *reinterpret_cast<const float4*>(&fk[r][f0 + 4 * g]);
            acc[4 * g + 0] += q.x * v; acc[4 * g + 1] += q.y * v;
            acc[4 * g + 2] += q.z * v; acc[4 * g + 3] += q.w * v;
        }
    }
    float* sp = S + (size_t)c * SST + tid;
    #pragma unroll
    for (int f = 0; f < 20; ++f) sp[(size_t)(f0 + f) * DD] = acc[f];
}

// ---------------- K4b: exclusive prefix-sum of chunk states within each batch
__global__ __launch_bounds__(256) void k4b_scan(
    const float* __restrict__ S, float* __restrict__ M)
{
    const int e = blockIdx.x * 256 + threadIdx.x;   // element in [0, SST)
    const int b = blockIdx.y;
    float run = 0.0f;
    for (int cc = 0; cc < NCB; ++cc) {
        size_t o = ((size_t)(b * NCB + cc)) * SST + e;
        M[o] = run;
        run += S[o];
    }
}

// ---------------- K4c: out = F_q @ M_prev + tril(F_q F_k^T) @ V + LTM
// grid (NC, 4): each block does a 16-row quarter of one chunk. acc[16] -> no spill.
__global__ __launch_bounds__(256) void k4c_out(
    const float* __restrict__ Fq, const float* __restrict__ Fk,
    const float* __restrict__ Fql, const float* __restrict__ V,
    const float* __restrict__ M, const float* __restrict__ ltm_mem,
    float* __restrict__ Tot)
{
    __shared__ __align__(16) float fq[16][FDIM];
    __shared__ __align__(16) float fkS[CC * 96];   // swizzled: [r][cx ^ ((r&7)<<2)], stride 96
    __shared__ __align__(16) float sc[16][68];
    const int c = blockIdx.x;
    const int h = blockIdx.y;
    const int r0 = h * 16;
    const int nrows = r0 + 16;          // causal extent of needed k rows
    const int tid = threadIdx.x;

    for (int i = tid; i < 16 * FDIM; i += 256) {
        int r = i / FDIM, cx = i - r * FDIM;
        fq[r][cx] = Fq[(size_t)(c * CC + r0 + r) * FDIM + cx];
    }
    for (int i = tid; i < nrows * FDIM; i += 256) {
        int r = i / FDIM, cx = i - r * FDIM;
        fkS[r * 96 + (cx ^ ((r & 7) << 2))] = Fk[(size_t)c * CC * FDIM + i];
    }
    __syncthreads();

    // 16x64 score tile (masked entries written zero)
    #pragma unroll
    for (int q = 0; q < 4; ++q) {
        int idx = tid + 256 * q;
        int i = idx >> 6, j = idx & 63;     // i uniform per wave, j = lane
        float s = 0.0f;
        if (r0 + i >= j) {
            const int sw = (j & 7) << 2;
            #pragma unroll
            for (int g = 0; g < 20; ++g) {
                float4 a = *reinterpret_cast<const float4*>(&fq[i][4 * g]);
                float4 b = *reinterpret_cast<const float4*>(&fkS[j * 96 + ((4 * g) ^ sw)]);
                s += a.x * b.x + a.y * b.y + a.z * b.z + a.w * b.w;
            }
        }
        sc[i][j] = s;
    }
    __syncthreads();

    const int d = tid;
    float acc[16];
    #pragma unroll
    for (int i = 0; i < 16; ++i) acc[i] = 0.0f;

    // inter-chunk: F_q @ M_prev
    const float* mp = M + (size_t)c * SST + d;
    #pragma unroll 2
    for (int g = 0; g < 20; ++g) {
        float m0 = mp[(size_t)(4 * g + 0) * DD];
        float m1 = mp[(size_t)(4 * g + 1) * DD];
        float m2 = mp[(size_t)(4 * g + 2) * DD];
        float m3 = mp[(size_t)(4 * g + 3) * DD];
        #pragma unroll
        for (int i = 0; i < 16; ++i) {
            float4 a = *reinterpret_cast<const float4*>(&fq[i][4 * g]);
            acc[i] += a.x * m0 + a.y * m1 + a.z * m2 + a.w * m3;
        }
    }
    // intra-chunk: scores @ V, only up to causal extent
    const float* vp = V + (size_t)c * CC * DD + d;
    const int j4max = nrows >> 2;
    #pragma unroll 2
    for (int j4 = 0; j4 < j4max; ++j4) {
        float v0 = vp[(size_t)(4 * j4 + 0) * DD];
        float v1 = vp[(size_t)(4 * j4 + 1) * DD];
        float v2 = vp[(size_t)(4 * j4 + 2) * DD];
        float v3 = vp[(size_t)(4 * j4 + 3) * DD];
        #pragma unroll
        for (int i = 0; i < 16; ++i) {
            float4 s4 = *reinterpret_cast<const float4*>(&sc[i][4 * j4]);
            acc[i] += s4.x * v0 + s4.y * v1 + s4.z * v2 + s4.w * v3;
        }
    }
    // LTM: stage Fql rows into sc, apply constant memory matrix
    float mre[16], mim[16];
    #pragma unroll
    for (int p = 0; p < 16; ++p) {
        mre[p] = ltm_mem[((size_t)p * DD + d) * 2];
        mim[p] = ltm_mem[((size_t)p * DD + d) * 2 + 1];
    }
    __syncthreads();
    for (int i = tid; i < 16 * 32; i += 256) {
        int r = i >> 5, p = i & 31;
        sc[r][p] = Fql[(size_t)(c * CC + r0 + r) * 32 + p];
    }
    __syncthreads();
    float* tp = Tot + (size_t)(c * CC + r0) * DD + d;
    #pragma unroll 1
    for (int i = 0; i < 16; ++i) {
        float a = acc[i];
        #pragma unroll
        for (int p = 0; p < 16; ++p)
            a += sc[i][2 * p] * mre[p] + sc[i][2 * p + 1] * mim[p];
        tp[(size_t)i * DD] = a;
    }
}

// ---------------- K5: LayerNorm + output projection (16 tokens/block)
__global__ __launch_bounds__(256) void k5_out(
    const float* __restrict__ Tot,
    const float* __restrict__ gln, const float* __restrict__ bln,
    const float* __restrict__ out_w, const float* __restrict__ out_b,
    float* __restrict__ out)
{
    __shared__ float hsn[DD][16];   // transposed: [k][t]
    const int tid = threadIdx.x;
    const int t0 = blockIdx.x * 16;
    const int w = tid >> 6, lane = tid & 63;
    {
        int r = 4 * w + (lane >> 4);    // token row 0..15
        int l4 = lane & 15;
        float vbuf[16];
        float s = 0.0f, s2 = 0.0f;
        const float4* src = reinterpret_cast<const float4*>(
            Tot + (size_t)(t0 + r) * DD + l4 * 16);
        #pragma unroll
        for (int g = 0; g < 4; ++g) {
            float4 v = src[g];
            vbuf[4 * g + 0] = v.x; vbuf[4 * g + 1] = v.y;
            vbuf[4 * g + 2] = v.z; vbuf[4 * g + 3] = v.w;
            s += v.x + v.y + v.z + v.w;
            s2 += v.x * v.x + v.y * v.y + v.z * v.z + v.w * v.w;
        }
        #pragma unroll
        for (int off = 1; off < 16; off <<= 1) {
            s  += __shfl_xor(s, off);
            s2 += __shfl_xor(s2, off);
        }
        float mu = s * (1.0f / 256.0f);
        float var = s2 * (1.0f / 256.0f) - mu * mu;
        float rstd = rsqrtf(var + 1e-5f);
        #pragma unroll
        for (int i = 0; i < 16; ++i) {
            int k = l4 * 16 + i;
            hsn[k][r] = (vbuf[i] - mu) * rstd * gln[k] + bln[k];
        }
    }
    __syncthreads();
    float acc[16];
    #pragma unroll
    for (int t = 0; t < 16; ++t) acc[t] = 0.0f;
    #pragma unroll 4
    for (int k = 0; k < DD; ++k) {
        float wv = out_w[(size_t)k * DD + tid];
        #pragma unroll
        for (int g = 0; g < 4; ++g) {
            float4 hv = *reinterpret_cast<const float4*>(&hsn[k][4 * g]);
            acc[4 * g + 0] += hv.x * wv;
            acc[4 * g + 1] += hv.y * wv;
            acc[4 * g + 2] += hv.z * wv;
            acc[4 * g + 3] += hv.w * wv;
        }
    }
    float ob = out_b[tid];
    #pragma unroll
    for (int t = 0; t < 16; ++t)
        out[(size_t)(t0 + t) * DD + tid] = acc[t] + ob;
}

extern "C" void kernel_launch(void* const* d_in, const int* in_sizes, int n_in,
                              void* d_out, int out_size, void* d_ws, size_t ws_size,
                              hipStream_t stream)
{
    (void)in_sizes; (void)n_in; (void)out_size; (void)ws_size;
    const float* x        = (const float*)d_in[0];
    const float* ke_w1    = (const float*)d_in[1];
    const float* ke_b1    = (const float*)d_in[2];
    const float* ke_w2    = (const float*)d_in[3];
    const float* ke_b2    = (const float*)d_in[4];
    const float* qe_w1    = (const float*)d_in[5];
    const float* qe_b1    = (const float*)d_in[6];
    const float* qe_w2    = (const float*)d_in[7];
    const float* qe_b2    = (const float*)d_in[8];
    const float* v_w      = (const float*)d_in[9];
    const float* v_b      = (const float*)d_in[10];
    const float* out_ln_g = (const float*)d_in[11];
    const float* out_ln_b = (const float*)d_in[12];
    const float* out_w    = (const float*)d_in[13];
    const float* out_b    = (const float*)d_in[14];
    const float* set_weights = (const float*)d_in[15];
    const float* pos_weight  = (const float*)d_in[16];
    const float* gate_w1  = (const float*)d_in[17];
    const float* gate_b1  = (const float*)d_in[18];
    const float* gate_w2  = (const float*)d_in[19];
    const float* gate_b2  = (const float*)d_in[20];
    const float* lke_w1   = (const float*)d_in[21];
    const float* lke_b1   = (const float*)d_in[22];
    const float* lke_w2   = (const float*)d_in[23];
    const float* lke_b2   = (const float*)d_in[24];
    const float* surprise_scale      = (const float*)d_in[25];
    const float* surprise_bias       = (const float*)d_in[26];
    const float* resonance_scale     = (const float*)d_in[27];
    const float* resonance_threshold = (const float*)d_in[28];
    const float* ltm_weight = (const float*)d_in[29];
    const float* pos_freqs  = (const float*)d_in[30];
    const float* ltm_mem    = (const float*)d_in[31];  // complex64 interleaved (16,256)
    const float* ltm_count  = (const float*)d_in[32];

    float* ws  = (float*)d_ws;
    float* H   = ws;                    // NT*896 floats
    float* V   = H   + (size_t)NT * HCOLS;
    float* Fk  = V   + (size_t)NT * DD;
    float* Fq  = Fk  + (size_t)NT * FDIM;
    float* Fql = Fq  + (size_t)NT * FDIM;
    float* Tot = Fql + (size_t)NT * 32;
    // chunk states alias H (H is dead after k2; NC*SST*2 = 2.62M floats < NT*896 = 3.67M)
    float* S   = H;
    float* M   = H + (size_t)NC * SST;

    k1_first<<<NT / 16, 256, 0, stream>>>(x, ke_w1, ke_b1, qe_w1, qe_b1, lke_w1, lke_b1,
                                          gate_w1, gate_b1, v_w, v_b, H, V);
    k2_second<<<NT / 4, 256, 0, stream>>>(H, ke_w2, ke_b2, qe_w2, qe_b2, lke_w2, lke_b2,
                                          gate_w2, gate_b2, set_weights, pos_weight,
                                          ltm_weight, ltm_count, pos_freqs, Fk, Fq, Fql);
    k3_scan<<<BB, 512, 0, stream>>>(Fk, resonance_scale, resonance_threshold,
                                    surprise_scale, surprise_bias);
    k4a_state<<<dim3(NC, 4), 256, 0, stream>>>(Fk, V, S);
    k4b_scan<<<dim3(SST / 256, BB), 256, 0, stream>>>(S, M);
    k4c_out<<<dim3(NC, 4), 256, 0, stream>>>(Fq, Fk, Fql, V, M, ltm_mem, Tot);
    k5_out<<<NT / 16, 256, 0, stream>>>(Tot, out_ln_g, out_ln_b, out_w, out_b, (float*)d_out);
}

// Round 5
// 173.021 us; speedup vs baseline: 1.8448x; 1.8448x over previous
//
#include <hip/hip_runtime.h>
#include <hip/hip_bf16.h>
#include <math.h>

#define BB 2
#define LL 2048
#define DD 256
#define NT (BB*LL)      // 4096 tokens
#define HCOLS 896       // ke(256) qe(256) lke(256) gate(128)
#define NCOLS 1152      // HCOLS + v(256)
#define KBIG 768        // split-bf16 concat K: [hi|lo-cross|hi-cross]
#define FDIM 80         // 32 bank + 8 joint + 32 pos + 8 pad
#define CC 64           // chunk length
#define NC (NT/CC)      // 64 chunks
#define NCB (LL/CC)     // 32 chunks per batch
#define SST (FDIM*DD)   // 20480 floats per chunk state
#define PI_F 3.14159265358979323846f

typedef __attribute__((ext_vector_type(8))) short s8frag;
typedef __attribute__((ext_vector_type(4))) float f4acc;

__device__ __forceinline__ float gelu_erf(float v) {
    return 0.5f * v * (1.0f + erff(v * 0.70710678118654752440f));
}
__device__ __forceinline__ float sigmoidf_(float v) {
    return 1.0f / (1.0f + expf(-v));
}

// ---------------- K0a: split x into bf16 hi/lo
__global__ __launch_bounds__(256) void k0_prep_x(
    const float* __restrict__ x, __hip_bfloat16* __restrict__ xhi,
    __hip_bfloat16* __restrict__ xlo)
{
    int idx = blockIdx.x * 256 + threadIdx.x;      // over NT*DD/4
    float4 v = reinterpret_cast<const float4*>(x)[idx];
    float vv[4] = {v.x, v.y, v.z, v.w};
    #pragma unroll
    for (int j = 0; j < 4; ++j) {
        __hip_bfloat16 h = __float2bfloat16(vv[j]);
        xhi[idx * 4 + j] = h;
        xlo[idx * 4 + j] = __float2bfloat16(vv[j] - __bfloat162float(h));
    }
}

// ---------------- K0b: build BbigT[n][k'] (n-major, K=768 = [W_hi | W_lo | W_hi]) + bcat
__global__ __launch_bounds__(256) void k0_prep_w(
    const float* __restrict__ ke_w1, const float* __restrict__ ke_b1,
    const float* __restrict__ qe_w1, const float* __restrict__ qe_b1,
    const float* __restrict__ lke_w1, const float* __restrict__ lke_b1,
    const float* __restrict__ gate_w1, const float* __restrict__ gate_b1,
    const float* __restrict__ v_w, const float* __restrict__ v_b,
    __hip_bfloat16* __restrict__ BT, float* __restrict__ bcat)
{
    int idx = blockIdx.x * 256 + threadIdx.x;      // over NCOLS*KBIG
    int n = idx / KBIG;
    int kp = idx - n * KBIG;
    int k = (kp < 256) ? kp : (kp < 512 ? kp - 256 : kp - 512);
    float w;
    if (n < 256)      w = ke_w1[k * 256 + n];
    else if (n < 512) w = qe_w1[k * 256 + (n - 256)];
    else if (n < 768) w = lke_w1[k * 256 + (n - 512)];
    else if (n < 896) w = gate_w1[k * 128 + (n - 768)];
    else              w = v_w[k * 256 + (n - 896)];
    __hip_bfloat16 hi = __float2bfloat16(w);
    // rows [0,256): W_hi ; [256,512): W_lo ; [512,768): W_hi  (pairs with A=[xhi|xhi|xlo])
    __hip_bfloat16 out = (kp >= 256 && kp < 512)
        ? __float2bfloat16(w - __bfloat162float(hi)) : hi;
    BT[(size_t)n * KBIG + kp] = out;
    if (kp == 0) {
        float bia;
        if (n < 256)      bia = ke_b1[n];
        else if (n < 512) bia = qe_b1[n - 256];
        else if (n < 768) bia = lke_b1[n - 512];
        else if (n < 896) bia = gate_b1[n - 768];
        else              bia = v_b[n - 896];
        bcat[n] = bia;
    }
}

// ---------------- K1: MFMA GEMM  C[4096][1152] = A[4096][768] @ B[768][1152]
// A = [xhi|xhi|xlo] (virtual), B given as BT[n][k]. Epilogue: +bias, gelu->H / raw->V.
__global__ __launch_bounds__(256) void k1_mfma(
    const __hip_bfloat16* __restrict__ xhi, const __hip_bfloat16* __restrict__ xlo,
    const __hip_bfloat16* __restrict__ BT, const float* __restrict__ bcat,
    float* __restrict__ H, float* __restrict__ V)
{
    __shared__ __align__(16) short As[128 * 32];
    __shared__ __align__(16) short Bs[128 * 32];
    const int tid = threadIdx.x;
    const int wave = tid >> 6, lane = tid & 63;
    const int wr = wave >> 1, wc = wave & 1;
    const int bm = blockIdx.x, bn = blockIdx.y;
    const int lg = lane >> 4, lr = lane & 15;

    f4acc acc[4][4] = {};

    for (int kt = 0; kt < KBIG / 32; ++kt) {
        const int k0 = kt * 32;
        const __hip_bfloat16* xsrc = (k0 < 512) ? xhi : xlo;
        const int kcol = (k0 < 512) ? (k0 & 255) : (k0 - 512);
        #pragma unroll
        for (int s = 0; s < 2; ++s) {
            int j = tid + 256 * s;
            int row = j >> 2, ch = j & 3;
            int sw = (row >> 1) & 3;
            uint4 va = *reinterpret_cast<const uint4*>(
                xsrc + (size_t)(bm * 128 + row) * DD + kcol + ch * 8);
            uint4 vb = *reinterpret_cast<const uint4*>(
                BT + (size_t)(bn * 128 + row) * KBIG + k0 + ch * 8);
            *reinterpret_cast<uint4*>(&As[row * 32 + ((ch ^ sw) << 3)]) = va;
            *reinterpret_cast<uint4*>(&Bs[row * 32 + ((ch ^ sw) << 3)]) = vb;
        }
        __syncthreads();
        s8frag a[4], b[4];
        #pragma unroll
        for (int i = 0; i < 4; ++i) {
            int arow = wr * 64 + i * 16 + lr;
            a[i] = *reinterpret_cast<const s8frag*>(
                &As[arow * 32 + ((lg ^ ((arow >> 1) & 3)) << 3)]);
            int brow = wc * 64 + i * 16 + lr;
            b[i] = *reinterpret_cast<const s8frag*>(
                &Bs[brow * 32 + ((lg ^ ((brow >> 1) & 3)) << 3)]);
        }
        #pragma unroll
        for (int mi = 0; mi < 4; ++mi)
            #pragma unroll
            for (int ni = 0; ni < 4; ++ni)
                acc[mi][ni] = __builtin_amdgcn_mfma_f32_16x16x32_bf16(
                    a[mi], b[ni], acc[mi][ni], 0, 0, 0);
        __syncthreads();
    }

    // epilogue: C row = bm*128 + wr*64 + mi*16 + lg*4 + r ; col = bn*128 + wc*64 + ni*16 + lr
    #pragma unroll
    for (int ni = 0; ni < 4; ++ni) {
        int n = bn * 128 + wc * 64 + ni * 16 + lr;
        float bia = bcat[n];
        #pragma unroll
        for (int mi = 0; mi < 4; ++mi) {
            #pragma unroll
            for (int r = 0; r < 4; ++r) {
                int m = bm * 128 + wr * 64 + mi * 16 + lg * 4 + r;
                float v = acc[mi][ni][r] + bia;
                if (n < HCOLS) H[(size_t)m * HCOLS + n] = gelu_erf(v);
                else           V[(size_t)m * DD + (n - HCOLS)] = v;
            }
        }
    }
}

// ---------------- K2: second layers -> phases -> feature vectors
__global__ __launch_bounds__(256) void k2_second(
    const float* __restrict__ H,
    const float* __restrict__ ke_w2, const float* __restrict__ ke_b2,
    const float* __restrict__ qe_w2, const float* __restrict__ qe_b2,
    const float* __restrict__ lke_w2, const float* __restrict__ lke_b2,
    const float* __restrict__ gate_w2, const float* __restrict__ gate_b2,
    const float* __restrict__ set_weights, const float* __restrict__ pos_weight,
    const float* __restrict__ ltm_weight, const float* __restrict__ ltm_count,
    const float* __restrict__ pos_freqs,
    float* __restrict__ Fk, float* __restrict__ Fq, float* __restrict__ Fql)
{
    __shared__ float hs[4][HCOLS];
    __shared__ float ph[4][49];   // 0..15 phi_k, 16..31 phi_q, 32..47 phi_ltm, 48 gate
    const int tid = threadIdx.x;
    const int w = tid >> 6;
    const int lane = tid & 63;
    const int t = blockIdx.x * 4 + w;

    for (int i = lane; i < HCOLS; i += 64) hs[w][i] = H[(size_t)t * HCOLS + i];
    __syncthreads();

    float val = 0.0f;
    if (lane < 16) {
        float a = ke_b2[lane];
        for (int k = 0; k < 256; ++k) a += hs[w][k] * ke_w2[k * 16 + lane];
        val = tanhf(a) * PI_F;
    } else if (lane < 32) {
        int o = lane - 16;
        float a = qe_b2[o];
        for (int k = 0; k < 256; ++k) a += hs[w][256 + k] * qe_w2[k * 16 + o];
        val = tanhf(a) * PI_F;
    } else if (lane < 48) {
        int o = lane - 32;
        float a = lke_b2[o];
        for (int k = 0; k < 256; ++k) a += hs[w][512 + k] * lke_w2[k * 16 + o];
        val = tanhf(a) * PI_F;
    } else if (lane == 48) {
        float a = gate_b2[0];
        for (int k = 0; k < 128; ++k) a += hs[w][768 + k] * gate_w2[k];
        val = sigmoidf_(a);
    }
    if (lane < 49) ph[w][lane] = val;
    __syncthreads();

    float sw[4];
    {
        float s0 = set_weights[0], s1 = set_weights[1], s2 = set_weights[2], s3 = set_weights[3];
        float mx = fmaxf(fmaxf(s0, s1), fmaxf(s2, s3));
        float e0 = expf(s0 - mx), e1 = expf(s1 - mx), e2 = expf(s2 - mx), e3 = expf(s3 - mx);
        float inv = 1.0f / (e0 + e1 + e2 + e3);
        sw[0] = e0 * inv; sw[1] = e1 * inv; sw[2] = e2 * inv; sw[3] = e3 * inv;
    }
    const float g = ph[w][48];
    const float aq = g * 0.2f;                                  // gate / (N_SETS+1)
    const float apos = (1.0f - g) * sigmoidf_(pos_weight[0]);
    const float altm = sigmoidf_(ltm_weight[0]) / sqrtf(fmaxf(ltm_count[0], 1.0f) * 16.0f);
    const int l = t & (LL - 1);
    float* fkr  = Fk  + (size_t)t * FDIM;
    float* fqr  = Fq  + (size_t)t * FDIM;
    float* fqlr = Fql + (size_t)t * 32;

    if (lane < 16) {
        int p = lane;
        float sk, ck; sincosf(ph[w][p], &sk, &ck);
        fkr[2 * p] = ck; fkr[2 * p + 1] = sk;
        float sq, cq; sincosf(ph[w][16 + p], &sq, &cq);
        float wq = aq * sw[p >> 2];
        fqr[2 * p] = wq * cq; fqr[2 * p + 1] = wq * sq;
        float sl, cl; sincosf(ph[w][32 + p], &sl, &cl);
        fqlr[2 * p] = altm * cl; fqlr[2 * p + 1] = altm * sl;
        float th = (float)l * pos_freqs[p] * (2.0f * PI_F);
        float sp, cp; sincosf(th, &sp, &cp);
        fkr[40 + 2 * p] = cp; fkr[41 + 2 * p] = sp;
        fqr[40 + 2 * p] = apos * cp; fqr[41 + 2 * p] = apos * sp;
    } else if (lane < 20) {
        int p = lane - 16;
        float pjk = ph[w][p] + ph[w][p + 4] + ph[w][p + 8] + ph[w][p + 12];
        float pjq = ph[w][16 + p] + ph[w][20 + p] + ph[w][24 + p] + ph[w][28 + p];
        float sjk, cjk; sincosf(pjk, &sjk, &cjk);
        float sjq, cjq; sincosf(pjq, &sjq, &cjq);
        fkr[32 + 2 * p] = cjk; fkr[33 + 2 * p] = sjk;
        fqr[32 + 2 * p] = aq * cjq; fqr[33 + 2 * p] = aq * sjq;
    } else if (lane < 24) {
        int p = lane - 20;
        fkr[72 + 2 * p] = 0.0f; fkr[73 + 2 * p] = 0.0f;
        fqr[72 + 2 * p] = 0.0f; fqr[73 + 2 * p] = 0.0f;
    }
}

// ---------------- K3a: exclusive scan of joint-key phasors -> write gate wg[token]
__device__ __forceinline__ int swz2048(int l) {
    return (l & ~31) | ((l ^ (l >> 5)) & 31);
}
__global__ __launch_bounds__(512) void k3a_scan(
    const float* __restrict__ Fk, float* __restrict__ wg,
    const float* __restrict__ resonance_scale, const float* __restrict__ resonance_threshold,
    const float* __restrict__ surprise_scale, const float* __restrict__ surprise_bias)
{
    __shared__ float km[8 * LL];
    const int b = blockIdx.x;
    const int tid = threadIdx.x;
    const int w = tid >> 6;     // series: 32 + w in Fk dims
    const int lane = tid & 63;
    {
        float v[32];
        float s = 0.0f;
        const float* src = Fk + (size_t)(b * LL) * FDIM + 32 + w;
        int l0 = lane * 32;
        #pragma unroll 4
        for (int i = 0; i < 32; ++i) { v[i] = src[(size_t)(l0 + i) * FDIM]; s += v[i]; }
        float local = s;
        #pragma unroll
        for (int off = 1; off < 64; off <<= 1) {
            float n = __shfl_up(s, off);
            if (lane >= off) s += n;
        }
        float run = s - local;   // exclusive base
        #pragma unroll 4
        for (int i = 0; i < 32; ++i) { km[w * LL + swz2048(l0 + i)] = run; run += v[i]; }
    }
    __syncthreads();
    const float sc  = fminf(fmaxf(resonance_scale[0], 1.0f), 20.0f);
    const float th  = fminf(fmaxf(resonance_threshold[0], 0.1f), 0.9f);
    const float ssc = surprise_scale[0];
    const float sbi = surprise_bias[0];
    for (int q = 0; q < 4; ++q) {
        int l = tid + 512 * q;
        int ls = swz2048(l);
        float rm = 0.0f;
        #pragma unroll
        for (int p = 0; p < 4; ++p) {
            float re = km[(2 * p) * LL + ls], im = km[(2 * p + 1) * LL + ls];
            rm += sqrtf(re * re + im * im);
        }
        rm *= 0.25f;
        float nr = rm / sqrtf(fmaxf((float)l, 1.0f));
        float sur = 0.5f * (1.0f - tanhf(sc * (nr - th)));
        wg[b * LL + l] = sigmoidf_(ssc * (sur - 0.5f) + sbi);
    }
}

// ---------------- K3b: apply write gate to Fk dims 0..39 (full grid)
__global__ __launch_bounds__(256) void k3b_apply(
    float* __restrict__ Fk, const float* __restrict__ wg)
{
    int idx = blockIdx.x * 256 + threadIdx.x;     // over NT*10 float4s
    int row = idx / 10, j = idx - row * 10;
    float w = wg[row];
    float4* p = reinterpret_cast<float4*>(Fk + (size_t)row * FDIM) + j;
    float4 v = *p;
    v.x *= w; v.y *= w; v.z *= w; v.w *= w;
    *p = v;
}

// ---------------- K4a: per-chunk key state S_c = F_k_c^T @ V_c   (80 x 256)
__global__ __launch_bounds__(256) void k4a_state(
    const float* __restrict__ Fk, const float* __restrict__ V, float* __restrict__ S)
{
    __shared__ __align__(16) float fk[CC][FDIM];
    const int c = blockIdx.x;
    const int f0 = blockIdx.y * 20;       // f quarter
    const int tid = threadIdx.x;          // = output dim d
    for (int i = tid; i < CC * FDIM; i += 256) {
        int r = i / FDIM, cx = i - r * FDIM;
        fk[r][cx] = Fk[(size_t)c * CC * FDIM + i];
    }
    __syncthreads();
    float acc[20];
    #pragma unroll
    for (int f = 0; f < 20; ++f) acc[f] = 0.0f;
    const float* vp = V + (size_t)c * CC * DD + tid;
    for (int r = 0; r < CC; ++r) {
        float v = vp[(size_t)r * DD];
        #pragma unroll
        for (int g = 0; g < 5; ++g) {
            float4 q = *reinterpret_cast<const float4*>(&fk[r][f0 + 4 * g]);
            acc[4 * g + 0] += q.x * v; acc[4 * g + 1] += q.y * v;
            acc[4 * g + 2] += q.z * v; acc[4 * g + 3] += q.w * v;
        }
    }
    float* sp = S + (size_t)c * SST + tid;
    #pragma unroll
    for (int f = 0; f < 20; ++f) sp[(size_t)(f0 + f) * DD] = acc[f];
}

// ---------------- K4b: exclusive prefix-sum of chunk states within each batch
__global__ __launch_bounds__(256) void k4b_scan(
    const float* __restrict__ S, float* __restrict__ M)
{
    const int e = blockIdx.x * 256 + threadIdx.x;   // element in [0, SST)
    const int b = blockIdx.y;
    float run = 0.0f;
    for (int cc = 0; cc < NCB; ++cc) {
        size_t o = ((size_t)(b * NCB + cc)) * SST + e;
        M[o] = run;
        run += S[o];
    }
}

// ---------------- K4c: out = F_q @ M_prev + tril(F_q F_k^T) @ V + LTM
__global__ __launch_bounds__(256) void k4c_out(
    const float* __restrict__ Fq, const float* __restrict__ Fk,
    const float* __restrict__ Fql, const float* __restrict__ V,
    const float* __restrict__ M, const float* __restrict__ ltm_mem,
    float* __restrict__ Tot)
{
    __shared__ __align__(16) float fq[16][FDIM];
    __shared__ __align__(16) float fkS[CC * 96];   // swizzled: [r][cx ^ ((r&7)<<2)], stride 96
    __shared__ __align__(16) float sc[16][68];
    const int c = blockIdx.x;
    const int h = blockIdx.y;
    const int r0 = h * 16;
    const int nrows = r0 + 16;          // causal extent of needed k rows
    const int tid = threadIdx.x;

    for (int i = tid; i < 16 * FDIM; i += 256) {
        int r = i / FDIM, cx = i - r * FDIM;
        fq[r][cx] = Fq[(size_t)(c * CC + r0 + r) * FDIM + cx];
    }
    for (int i = tid; i < nrows * FDIM; i += 256) {
        int r = i / FDIM, cx = i - r * FDIM;
        fkS[r * 96 + (cx ^ ((r & 7) << 2))] = Fk[(size_t)c * CC * FDIM + i];
    }
    __syncthreads();

    // 16x64 score tile (masked entries written zero)
    #pragma unroll
    for (int q = 0; q < 4; ++q) {
        int idx = tid + 256 * q;
        int i = idx >> 6, j = idx & 63;
        float s = 0.0f;
        if (r0 + i >= j) {
            const int sw = (j & 7) << 2;
            #pragma unroll
            for (int g = 0; g < 20; ++g) {
                float4 a = *reinterpret_cast<const float4*>(&fq[i][4 * g]);
                float4 b = *reinterpret_cast<const float4*>(&fkS[j * 96 + ((4 * g) ^ sw)]);
                s += a.x * b.x + a.y * b.y + a.z * b.z + a.w * b.w;
            }
        }
        sc[i][j] = s;
    }
    __syncthreads();

    const int d = tid;
    float acc[16];
    #pragma unroll
    for (int i = 0; i < 16; ++i) acc[i] = 0.0f;

    // inter-chunk: F_q @ M_prev
    const float* mp = M + (size_t)c * SST + d;
    #pragma unroll 2
    for (int g = 0; g < 20; ++g) {
        float m0 = mp[(size_t)(4 * g + 0) * DD];
        float m1 = mp[(size_t)(4 * g + 1) * DD];
        float m2 = mp[(size_t)(4 * g + 2) * DD];
        float m3 = mp[(size_t)(4 * g + 3) * DD];
        #pragma unroll
        for (int i = 0; i < 16; ++i) {
            float4 a = *reinterpret_cast<const float4*>(&fq[i][4 * g]);
            acc[i] += a.x * m0 + a.y * m1 + a.z * m2 + a.w * m3;
        }
    }
    // intra-chunk: scores @ V, only up to causal extent
    const float* vp = V + (size_t)c * CC * DD + d;
    const int j4max = nrows >> 2;
    #pragma unroll 2
    for (int j4 = 0; j4 < j4max; ++j4) {
        float v0 = vp[(size_t)(4 * j4 + 0) * DD];
        float v1 = vp[(size_t)(4 * j4 + 1) * DD];
        float v2 = vp[(size_t)(4 * j4 + 2) * DD];
        float v3 = vp[(size_t)(4 * j4 + 3) * DD];
        #pragma unroll
        for (int i = 0; i < 16; ++i) {
            float4 s4 = *reinterpret_cast<const float4*>(&sc[i][4 * j4]);
            acc[i] += s4.x * v0 + s4.y * v1 + s4.z * v2 + s4.w * v3;
        }
    }
    // LTM epilogue
    float mre[16], mim[16];
    #pragma unroll
    for (int p = 0; p < 16; ++p) {
        mre[p] = ltm_mem[((size_t)p * DD + d) * 2];
        mim[p] = ltm_mem[((size_t)p * DD + d) * 2 + 1];
    }
    __syncthreads();
    for (int i = tid; i < 16 * 32; i += 256) {
        int r = i >> 5, p = i & 31;
        sc[r][p] = Fql[(size_t)(c * CC + r0 + r) * 32 + p];
    }
    __syncthreads();
    float* tp = Tot + (size_t)(c * CC + r0) * DD + d;
    #pragma unroll 1
    for (int i = 0; i < 16; ++i) {
        float a = acc[i];
        #pragma unroll
        for (int p = 0; p < 16; ++p)
            a += sc[i][2 * p] * mre[p] + sc[i][2 * p + 1] * mim[p];
        tp[(size_t)i * DD] = a;
    }
}

// ---------------- K5: LayerNorm + output projection (16 tokens/block)
__global__ __launch_bounds__(256) void k5_out(
    const float* __restrict__ Tot,
    const float* __restrict__ gln, const float* __restrict__ bln,
    const float* __restrict__ out_w, const float* __restrict__ out_b,
    float* __restrict__ out)
{
    __shared__ float hsn[DD][16];   // transposed [k][t], col index XOR-swizzled by (k>>4)&3
    const int tid = threadIdx.x;
    const int t0 = blockIdx.x * 16;
    const int w = tid >> 6, lane = tid & 63;
    {
        int r = 4 * w + (lane >> 4);    // token row 0..15
        int l4 = lane & 15;
        float vbuf[16];
        float s = 0.0f, s2 = 0.0f;
        const float4* src = reinterpret_cast<const float4*>(
            Tot + (size_t)(t0 + r) * DD + l4 * 16);
        #pragma unroll
        for (int g = 0; g < 4; ++g) {
            float4 v = src[g];
            vbuf[4 * g + 0] = v.x; vbuf[4 * g + 1] = v.y;
            vbuf[4 * g + 2] = v.z; vbuf[4 * g + 3] = v.w;
            s += v.x + v.y + v.z + v.w;
            s2 += v.x * v.x + v.y * v.y + v.z * v.z + v.w * v.w;
        }
        #pragma unroll
        for (int off = 1; off < 16; off <<= 1) {
            s  += __shfl_xor(s, off);
            s2 += __shfl_xor(s2, off);
        }
        float mu = s * (1.0f / 256.0f);
        float var = s2 * (1.0f / 256.0f) - mu * mu;
        float rstd = rsqrtf(var + 1e-5f);
        const int swc = (l4 & 3) << 2;   // = ((k>>4)&3)<<2 for k = l4*16+i
        #pragma unroll
        for (int i = 0; i < 16; ++i) {
            int k = l4 * 16 + i;
            hsn[k][r ^ swc] = (vbuf[i] - mu) * rstd * gln[k] + bln[k];
        }
    }
    __syncthreads();
    float acc[16];
    #pragma unroll
    for (int t = 0; t < 16; ++t) acc[t] = 0.0f;
    #pragma unroll 4
    for (int k = 0; k < DD; ++k) {
        float wv = out_w[(size_t)k * DD + tid];
        const int swc = ((k >> 4) & 3) << 2;
        #pragma unroll
        for (int g = 0; g < 4; ++g) {
            // column block (4g)^swc holds tokens 4g..4g+3 (swc only flips bits 2-3)
            float4 hv = *reinterpret_cast<const float4*>(&hsn[k][(4 * g) ^ swc]);
            acc[4 * g + 0] += hv.x * wv;
            acc[4 * g + 1] += hv.y * wv;
            acc[4 * g + 2] += hv.z * wv;
            acc[4 * g + 3] += hv.w * wv;
        }
    }
    float ob = out_b[tid];
    #pragma unroll
    for (int t = 0; t < 16; ++t)
        out[(size_t)(t0 + t) * DD + tid] = acc[t] + ob;
}

extern "C" void kernel_launch(void* const* d_in, const int* in_sizes, int n_in,
                              void* d_out, int out_size, void* d_ws, size_t ws_size,
                              hipStream_t stream)
{
    (void)in_sizes; (void)n_in; (void)out_size; (void)ws_size;
    const float* x        = (const float*)d_in[0];
    const float* ke_w1    = (const float*)d_in[1];
    const float* ke_b1    = (const float*)d_in[2];
    const float* ke_w2    = (const float*)d_in[3];
    const float* ke_b2    = (const float*)d_in[4];
    const float* qe_w1    = (const float*)d_in[5];
    const float* qe_b1    = (const float*)d_in[6];
    const float* qe_w2    = (const float*)d_in[7];
    const float* qe_b2    = (const float*)d_in[8];
    const float* v_w      = (const float*)d_in[9];
    const float* v_b      = (const float*)d_in[10];
    const float* out_ln_g = (const float*)d_in[11];
    const float* out_ln_b = (const float*)d_in[12];
    const float* out_w    = (const float*)d_in[13];
    const float* out_b    = (const float*)d_in[14];
    const float* set_weights = (const float*)d_in[15];
    const float* pos_weight  = (const float*)d_in[16];
    const float* gate_w1  = (const float*)d_in[17];
    const float* gate_b1  = (const float*)d_in[18];
    const float* gate_w2  = (const float*)d_in[19];
    const float* gate_b2  = (const float*)d_in[20];
    const float* lke_w1   = (const float*)d_in[21];
    const float* lke_b1   = (const float*)d_in[22];
    const float* lke_w2   = (const float*)d_in[23];
    const float* lke_b2   = (const float*)d_in[24];
    const float* surprise_scale      = (const float*)d_in[25];
    const float* surprise_bias       = (const float*)d_in[26];
    const float* resonance_scale     = (const float*)d_in[27];
    const float* resonance_threshold = (const float*)d_in[28];
    const float* ltm_weight = (const float*)d_in[29];
    const float* pos_freqs  = (const float*)d_in[30];
    const float* ltm_mem    = (const float*)d_in[31];  // complex64 interleaved (16,256)
    const float* ltm_count  = (const float*)d_in[32];

    float* ws  = (float*)d_ws;
    float* H   = ws;                    // NT*896 floats
    float* V   = H   + (size_t)NT * HCOLS;
    float* Fk  = V   + (size_t)NT * DD;
    float* Fq  = Fk  + (size_t)NT * FDIM;
    float* Fql = Fq  + (size_t)NT * FDIM;
    float* Tot = Fql + (size_t)NT * 32;
    // chunk states alias H (dead after k2): S+M = 2.62M floats < NT*896 = 3.67M
    float* S   = H;
    float* M   = H + (size_t)NC * SST;
    // prep buffers alias [Fk .. Tot+NT*DD) (7.34MB region, dead until k2 writes it)
    __hip_bfloat16* xhi = (__hip_bfloat16*)Fk;           // NT*DD bf16
    __hip_bfloat16* xlo = xhi + (size_t)NT * DD;         // NT*DD bf16
    __hip_bfloat16* BT  = xlo + (size_t)NT * DD;         // 1152*768 bf16
    float* bcat = (float*)(BT + (size_t)NCOLS * KBIG);   // 1152 f32
    float* wg   = bcat + NCOLS;                           // NT f32 (k3a->k3b only)

    k0_prep_x<<<(NT * DD / 4) / 256, 256, 0, stream>>>(x, xhi, xlo);
    k0_prep_w<<<(NCOLS * KBIG) / 256, 256, 0, stream>>>(ke_w1, ke_b1, qe_w1, qe_b1,
                                                        lke_w1, lke_b1, gate_w1, gate_b1,
                                                        v_w, v_b, BT, bcat);
    k1_mfma<<<dim3(NT / 128, NCOLS / 128), 256, 0, stream>>>(xhi, xlo, BT, bcat, H, V);
    k2_second<<<NT / 4, 256, 0, stream>>>(H, ke_w2, ke_b2, qe_w2, qe_b2, lke_w2, lke_b2,
                                          gate_w2, gate_b2, set_weights, pos_weight,
                                          ltm_weight, ltm_count, pos_freqs, Fk, Fq, Fql);
    k3a_scan<<<BB, 512, 0, stream>>>(Fk, wg, resonance_scale, resonance_threshold,
                                     surprise_scale, surprise_bias);
    k3b_apply<<<(NT * 10) / 256, 256, 0, stream>>>(Fk, wg);
    k4a_state<<<dim3(NC, 4), 256, 0, stream>>>(Fk, V, S);
    k4b_scan<<<dim3(SST / 256, BB), 256, 0, stream>>>(S, M);
    k4c_out<<<dim3(NC, 4), 256, 0, stream>>>(Fq, Fk, Fql, V, M, ltm_mem, Tot);
    k5_out<<<NT / 16, 256, 0, stream>>>(Tot, out_ln_g, out_ln_b, out_w, out_b, (float*)d_out);
}